// Round 17
// baseline (3892.353 us; speedup 1.0000x reference)
//
#include <hip/hip_runtime.h>
#include <stdint.h>

// Echo-state network (fp32 in, fp32 out). Round 17: R14 structure + direct
// register B-loads. R16 post-mortem: K-split waves spilled (WRITE_SIZE 6.9 ->
// 139.7 MB/step = scratch stores) and serialized MFMA (one wave per chunk);
// reverted. R14 model: LDS-bound (~72 KB/chunk/block; 40 KB of it is
// B-fragment staging+reads, with 4 waves reading IDENTICAL fragments).
// Fix: B (W_res/W_in) fragments loaded global->register as f16x8 via the
// vmem/L1 pipe (parallel to LDS), double-buffered one chunk ahead; LDS keeps
// only the A (state) tiles (18.4 KB/block). Numerics identical: (hi, lo*4096)
// f16 pairs, 3 MFMAs/product, same summation order.

typedef _Float16 f16;
typedef _Float16 f16x8 __attribute__((ext_vector_type(8)));
typedef float floatx4 __attribute__((ext_vector_type(4)));

#define N_TOT 256
#define T_TOT 70
#define V_TOT 64
#define B_TOT 6
#define H_TOT 1024
#define C_TOT 4
#define F_TOT (B_TOT * H_TOT)
#define G_TOT 192
#define LDA 72
#define LO_SCALE 4096.0f
#define LO_INV   (1.0f / 4096.0f)

union H8 { f16 h[8]; uint4 v; };

__global__ __launch_bounds__(256)
void split_f32(const float* __restrict__ src, f16* __restrict__ hi,
               f16* __restrict__ lo, int n)
{
    const int i = (blockIdx.x * 256 + threadIdx.x) * 8;
    if (i + 8 > n) return;
    const float4 a = *(const float4*)&src[i];
    const float4 b = *(const float4*)&src[i + 4];
    const float x[8] = {a.x, a.y, a.z, a.w, b.x, b.y, b.z, b.w};
    H8 H, L;
#pragma unroll
    for (int j = 0; j < 8; ++j) {
        const f16 h = (f16)x[j];
        H.h[j] = h;
        L.h[j] = (f16)((x[j] - (float)h) * LO_SCALE);
    }
    *(uint4*)&hi[i] = H.v;
    *(uint4*)&lo[i] = L.v;
}

__global__ __launch_bounds__(256)
void head_reduce(const float* __restrict__ part,
                 const float* __restrict__ b_lin,
                 float* __restrict__ logits,
                 float* __restrict__ preds)
{
    const int t = blockIdx.x;
    const int n = threadIdx.x;

    float a0 = b_lin[t * C_TOT + 0];
    float a1 = b_lin[t * C_TOT + 1];
    float a2 = b_lin[t * C_TOT + 2];
    float a3 = b_lin[t * C_TOT + 3];

    const float* p = part + (((size_t)t * G_TOT) * N_TOT + n) * C_TOT;
    for (int g = 0; g < G_TOT; ++g) {
        const float4 v = *(const float4*)&p[(size_t)g * N_TOT * C_TOT];
        a0 += v.x; a1 += v.y; a2 += v.z; a3 += v.w;
    }

    float4 o = {a0, a1, a2, a3};
    *(float4*)&logits[((size_t)t * N_TOT + n) * C_TOT] = o;

    int arg = 0;
    float best = a0;
    if (a1 > best) { best = a1; arg = 1; }
    if (a2 > best) { best = a2; arg = 2; }
    if (a3 > best) { best = a3; arg = 3; }
    preds[(size_t)t * N_TOT + n] = (float)arg;
}

// ---------------------------------------------------------------------------
// Step: tile 64(M) x 32(I), grid = 768. Wave wm owns M-rows wm*16..+15 and
// computes acc[nf] over the full 32 I-cols (R14 assignment). A (state) via
// LDS staging with register prefetch; B (weights) DIRECT global->register,
// ping-pong double-buffered per chunk. 3 MFMAs per product (hi/lo scheme).
// ---------------------------------------------------------------------------
__global__ __launch_bounds__(256, 3)
void esn_step_fused(const f16* __restrict__ Xhi,   const f16* __restrict__ Xlo,
                    const f16* __restrict__ Whi,   const f16* __restrict__ Wlo,
                    const f16* __restrict__ Wihi,  const f16* __restrict__ Wilo,
                    const f16* __restrict__ shi_p, const f16* __restrict__ slo_p,
                    f16* __restrict__ shi_n,       f16* __restrict__ slo_n,
                    const float* __restrict__ W_lin, float* __restrict__ part,
                    int t, int first)
{
    __shared__ f16 As_hi[64 * LDA];
    __shared__ f16 As_lo[64 * LDA];

    const int id  = blockIdx.x;
    const int b   = id >> 7;
    const int rem = id & 127;
    const int mt  = rem >> 5;
    const int it  = rem & 31;

    const int tid  = threadIdx.x;
    const int wm   = tid >> 6;        // wave = M-slab (R14 assignment)
    const int lane = tid & 63;
    const int l16  = lane & 15;
    const int oct  = lane >> 4;

    const int ra = tid >> 2;          // A staging row 0..63
    const int ca = (tid & 3) << 4;    // A staging col {0,16,32,48}

    floatx4 acc[2], accl[2];
#pragma unroll
    for (int j = 0; j < 2; ++j) { acc[j] = (floatx4)(0.0f); accl[j] = (floatx4)(0.0f); }

    // B fragment row offsets (per-lane, within W row-major [.,H] / [.,V])
    const size_t browH[2] = { (size_t)(0 * 16 + l16) * H_TOT,
                              (size_t)(1 * 16 + l16) * H_TOT };

    if (!first) {
        const f16* Ah = shi_p + (size_t)(b * N_TOT + mt * 64 + ra) * H_TOT + ca;
        const f16* Al = slo_p + (size_t)(b * N_TOT + mt * 64 + ra) * H_TOT + ca;
        const f16* Wh = Whi + (size_t)(b * H_TOT + it * 32) * H_TOT;
        const f16* Wl = Wlo + (size_t)(b * H_TOT + it * 32) * H_TOT;

        uint4 pah0, pah1, pal0, pal1;
        f16x8 bh0[2][2], bl0[2][2], bh1[2][2], bl1[2][2]; // [kk2][nf]

#define LOAD_A(J0)                                       \
        do {                                             \
            pah0 = *(const uint4*)&Ah[(J0) + 0];         \
            pah1 = *(const uint4*)&Ah[(J0) + 8];         \
            pal0 = *(const uint4*)&Al[(J0) + 0];         \
            pal1 = *(const uint4*)&Al[(J0) + 8];         \
        } while (0)
#define LOAD_B(J0, BH, BL)                                               \
        do {                                                             \
            _Pragma("unroll")                                            \
            for (int k2 = 0; k2 < 2; ++k2)                               \
                _Pragma("unroll")                                        \
                for (int nf = 0; nf < 2; ++nf) {                         \
                    const size_t o = browH[nf] + (J0) + k2 * 32 + oct * 8; \
                    BH[k2][nf] = *(const f16x8*)&Wh[o];                  \
                    BL[k2][nf] = *(const f16x8*)&Wl[o];                  \
                }                                                        \
        } while (0)
#define STORE_A()                                        \
        do {                                             \
            *(uint4*)&As_hi[ra * LDA + ca]     = pah0;   \
            *(uint4*)&As_hi[ra * LDA + ca + 8] = pah1;   \
            *(uint4*)&As_lo[ra * LDA + ca]     = pal0;   \
            *(uint4*)&As_lo[ra * LDA + ca + 8] = pal1;   \
        } while (0)
#define COMPUTE(BH, BL)                                                        \
        do {                                                                   \
            _Pragma("unroll")                                                  \
            for (int k2 = 0; k2 < 2; ++k2) {                                   \
                const int ar = (wm * 16 + l16) * LDA + k2 * 32 + oct * 8;      \
                const f16x8 ah = *(const f16x8*)&As_hi[ar];                    \
                const f16x8 al = *(const f16x8*)&As_lo[ar];                    \
                _Pragma("unroll")                                              \
                for (int nf = 0; nf < 2; ++nf) {                               \
                    acc[nf]  = __builtin_amdgcn_mfma_f32_16x16x32_f16(ah, BH[k2][nf], acc[nf], 0, 0, 0);  \
                    accl[nf] = __builtin_amdgcn_mfma_f32_16x16x32_f16(ah, BL[k2][nf], accl[nf], 0, 0, 0); \
                    accl[nf] = __builtin_amdgcn_mfma_f32_16x16x32_f16(al, BH[k2][nf], accl[nf], 0, 0, 0); \
                }                                                              \
            }                                                                  \
        } while (0)

        LOAD_A(0);
        LOAD_B(0, bh0, bl0);
        for (int kc = 0; kc < 16; kc += 2) {
            // even chunk: compute with set0, prefetch set1
            if (kc) __syncthreads();
            STORE_A();
            __syncthreads();
            LOAD_A((kc + 1) * 64);
            LOAD_B((kc + 1) * 64, bh1, bl1);
            COMPUTE(bh0, bl0);
            // odd chunk: compute with set1, prefetch set0
            __syncthreads();
            STORE_A();
            __syncthreads();
            if (kc + 2 < 16) {
                LOAD_A((kc + 2) * 64);
                LOAD_B((kc + 2) * 64, bh0, bl0);
            }
            COMPUTE(bh1, bl1);
        }
#undef LOAD_A
#undef LOAD_B
#undef STORE_A
#undef COMPUTE
        __syncthreads();
    }

    // ---- input term: += X_t * W_in[b]^T  (K = V = 64) ----
    {
        // B (W_in) fragments direct from global
        const f16* Wih = Wihi + (size_t)(b * H_TOT + it * 32) * V_TOT;
        const f16* Wil = Wilo + (size_t)(b * H_TOT + it * 32) * V_TOT;
        f16x8 bh[2][2], bl[2][2];
#pragma unroll
        for (int k2 = 0; k2 < 2; ++k2)
#pragma unroll
            for (int nf = 0; nf < 2; ++nf) {
                const size_t o = (size_t)(nf * 16 + l16) * V_TOT + k2 * 32 + oct * 8;
                bh[k2][nf] = *(const f16x8*)&Wih[o];
                bl[k2][nf] = *(const f16x8*)&Wil[o];
            }

        const size_t xb = ((size_t)(mt * 64 + ra) * T_TOT + t) * V_TOT + ca;
        *(uint4*)&As_hi[ra * LDA + ca]     = *(const uint4*)&Xhi[xb];
        *(uint4*)&As_hi[ra * LDA + ca + 8] = *(const uint4*)&Xhi[xb + 8];
        *(uint4*)&As_lo[ra * LDA + ca]     = *(const uint4*)&Xlo[xb];
        *(uint4*)&As_lo[ra * LDA + ca + 8] = *(const uint4*)&Xlo[xb + 8];
        __syncthreads();

#pragma unroll
        for (int k2 = 0; k2 < 2; ++k2) {
            const int ar = (wm * 16 + l16) * LDA + k2 * 32 + oct * 8;
            const f16x8 ah = *(const f16x8*)&As_hi[ar];
            const f16x8 al = *(const f16x8*)&As_lo[ar];
#pragma unroll
            for (int nf = 0; nf < 2; ++nf) {
                acc[nf]  = __builtin_amdgcn_mfma_f32_16x16x32_f16(ah, bh[k2][nf], acc[nf], 0, 0, 0);
                accl[nf] = __builtin_amdgcn_mfma_f32_16x16x32_f16(ah, bl[k2][nf], accl[nf], 0, 0, 0);
                accl[nf] = __builtin_amdgcn_mfma_f32_16x16x32_f16(al, bh[k2][nf], accl[nf], 0, 0, 0);
            }
        }
    }

    // ---- epilogue: tanh -> split-store state; head partial -> part[] ----
    const int nbase = mt * 64;
    const int ibase = it * 32;

    const float* wl = W_lin + (size_t)t * C_TOT * F_TOT + b * H_TOT + ibase;
    float w[4][2];
#pragma unroll
    for (int c = 0; c < 4; ++c)
#pragma unroll
        for (int nf = 0; nf < 2; ++nf)
            w[c][nf] = wl[(size_t)c * F_TOT + nf * 16 + l16];

    float sval[2][4];
#pragma unroll
    for (int nf = 0; nf < 2; ++nf)
#pragma unroll
        for (int r = 0; r < 4; ++r) {
            const int m  = wm * 16 + oct * 4 + r;
            const int ii = nf * 16 + l16;
            const float s = tanhf(acc[nf][r] + accl[nf][r] * LO_INV);
            sval[nf][r] = s;
            const f16 h = (f16)s;
            const size_t oidx = (size_t)(b * N_TOT + nbase + m) * H_TOT + ibase + ii;
            shi_n[oidx] = h;
            slo_n[oidx] = (f16)((s - (float)h) * LO_SCALE);
        }

    const int g = b * 32 + it;
#pragma unroll
    for (int r = 0; r < 4; ++r) {
        float v[4];
#pragma unroll
        for (int c = 0; c < 4; ++c) {
            float x = sval[0][r] * w[c][0] + sval[1][r] * w[c][1];
            x += __shfl_xor(x, 1);
            x += __shfl_xor(x, 2);
            x += __shfl_xor(x, 4);
            x += __shfl_xor(x, 8);
            v[c] = x;
        }
        if (l16 == 0) {
            const int n = nbase + wm * 16 + oct * 4 + r;
            float4 o = {v[0], v[1], v[2], v[3]};
            *(float4*)&part[(((size_t)t * G_TOT + g) * N_TOT + n) * C_TOT] = o;
        }
    }
}

extern "C" void kernel_launch(void* const* d_in, const int* in_sizes, int n_in,
                              void* d_out, int out_size, void* d_ws, size_t ws_size,
                              hipStream_t stream) {
    const float* X     = (const float*)d_in[0]; // [256,70,64]
    const float* W_res = (const float*)d_in[1]; // [6,1024,1024]
    const float* W_in  = (const float*)d_in[2]; // [6,1024,64]
    const float* W_lin = (const float*)d_in[3]; // [70,4,6144]
    const float* b_lin = (const float*)d_in[4]; // [70,4]

    float* out    = (float*)d_out;
    float* logits = out;
    float* preds  = out + (size_t)T_TOT * N_TOT * C_TOT;

    const size_t nWres = (size_t)B_TOT * H_TOT * H_TOT;
    const size_t nWin  = (size_t)B_TOT * H_TOT * V_TOT;
    const size_t nX    = (size_t)N_TOT * T_TOT * V_TOT;
    const size_t nS    = (size_t)B_TOT * N_TOT * H_TOT;

    f16* p    = (f16*)d_ws;
    f16* Whi  = p;  p += nWres;
    f16* Wlo  = p;  p += nWres;
    f16* Wihi = p;  p += nWin;
    f16* Wilo = p;  p += nWin;
    f16* Xhi  = p;  p += nX;
    f16* Xlo  = p;  p += nX;
    f16* sAh  = p;  p += nS;
    f16* sAl  = p;  p += nS;
    f16* sBh  = p;  p += nS;
    f16* sBl  = p;  p += nS;
    float* part = (float*)p;   // 55 MB; total ws use ~99 MB

    split_f32<<<(int)(nWres / 2048), 256, 0, stream>>>(W_res, Whi, Wlo, (int)nWres);
    split_f32<<<(int)(nWin  / 2048), 256, 0, stream>>>(W_in, Wihi, Wilo, (int)nWin);
    split_f32<<<(int)(nX    / 2048), 256, 0, stream>>>(X, Xhi, Xlo, (int)nX);

    for (int t = 0; t < T_TOT; ++t) {
        const f16 *ph, *pl;
        f16 *nh, *nl;
        if (t & 1) { ph = sBh; pl = sBl; nh = sAh; nl = sAl; }
        else       { ph = sAh; pl = sAl; nh = sBh; nl = sBl; }
        esn_step_fused<<<B_TOT * 4 * 32, 256, 0, stream>>>(
            Xhi, Xlo, Whi, Wlo, Wihi, Wilo, ph, pl, nh, nl,
            W_lin, part, t, t == 0 ? 1 : 0);
    }
    head_reduce<<<T_TOT, 256, 0, stream>>>(part, b_lin, logits, preds);
}